// Round 1
// baseline (1633.688 us; speedup 1.0000x reference)
//
#include <hip/hip_runtime.h>

namespace {

constexpr int kB  = 16;
constexpr int kNC = 31;
constexpr int kNX = 256;   // rows (H)
constexpr int kNY = 256;   // cols (W)
constexpr int kNO = 3;
constexpr int kKS = 17;
constexpr int NOC = kNO * kNC;   // 93

constexpr int TX = 64;           // output cols per block
constexpr int TY = 64;           // output rows per block
constexpr int HTY = TY + 8;      // 72 staged rows (halo +-4)
constexpr int XP   = 80;         // pitch (floats): mult of 4 -> all b128 aligned
constexpr int W12  = 12;         // expanded taps (9 + residual shift 0..3)
constexpr int NSTG = 6;          // ceil(72*19 / 256) staging slots per thread

// ---------------------------------------------------------------------------
// prep: expand each 9-tap weight row to 12 taps with the residual shift rs
// pre-applied (w12[d'] = relu(w[d'-rs]) for d' in [rs,rs+9), else 0), and
// write soaTab[oc] = so & ~3 (the aligned part of the shift, used in staging).
// ---------------------------------------------------------------------------
__global__ void prep(const float* __restrict__ vk, const int* __restrict__ loc,
                     float* __restrict__ w12, int* __restrict__ soaTab)
{
    int i = blockIdx.x * 256 + threadIdx.x;
    if (i < NOC * 9 * W12) {
        int row = i / W12;             // row = oc*9 + dy
        int dp  = i - row * W12;       // d' in [0,12)
        int oc  = row / 9;
        // locations[oc*81] = ((oc*17 + 4)*17) + cx - 4  ->  so = cx - 4
        int so = loc[oc * 81] - (oc * kKS + 4) * kKS;   // in [0,8]
        int rs = so & 3;
        float v = 0.0f;
        if (dp >= rs && dp < rs + 9) {
            float t = vk[row * 9 + (dp - rs)];
            v = t > 0.0f ? t : 0.0f;
        }
        w12[i] = v;
    }
    if (i < NOC) {
        int so = loc[i * 81] - (i * kKS + 4) * kKS;
        soaTab[i] = so & ~3;           // in {0,4,8}
    }
}

// One (batch, order, 64x64 tile) per block. 256 threads as 16x16: each thread
// owns 4 cols x 4 rows. Tile staged pre-shifted by soa -> compute reads are
// STATIC aligned ds_read_b128; residual shift lives in the 12-tap weights.
//
// v2: double-buffered LDS + register prefetch (T14). Channel c+1's global
// loads are issued BEFORE channel c's compute (latency hides under ~3456
// cycles of FMA); ds_write to the other buffer after compute; ONE barrier
// per channel instead of two. Staging address math hoisted out of the loop.
__global__ __launch_bounds__(256, 3)
void disperse_conv(const float* __restrict__ x,
                   const float* __restrict__ w12,
                   const int* __restrict__ soaTab,
                   float* __restrict__ out)
{
    __shared__ __align__(16) float xtile[2][HTY * XP];   // 2 x 23,040 B

    const int tid = threadIdx.x;
    const int x0 = blockIdx.x * TX;
    const int y0 = blockIdx.y * TY;
    const int bz = blockIdx.z;         // 48, order-adjacent: bz = b*3 + o
    const int b  = bz / 3;             // -> 3 orders of same (b,tile) run
    const int o  = bz - 3 * b;         //    together, L2/L3 absorbs x re-read

    const int tx = tid & 15;           // 16 threads across x
    const int ty = tid >> 4;           // 16 threads down y
    const int xo = tx * 4;             // 4 consecutive output cols per thread

    // ---- per-thread staging descriptors (channel-invariant) ----
    int  ldsOff[NSTG];                 // LDS float offset of this slot
    int  rowOff[NSTG];                 // gy * kNY (garbage when !okY, unused)
    int  gxBase[NSTG];                 // x0 - 8 + mc*4 (add soa per channel)
    bool wr[NSTG];                     // slot < HTY*19 -> participates in write
    bool okY[NSTG];                    // wr && gy in range -> may load
    #pragma unroll
    for (int it = 0; it < NSTG; ++it) {
        int i = it * 256 + tid;
        bool vslot = (i < HTY * 19);
        int ii = vslot ? i : 0;
        int r  = ii / 19;
        int mc = ii - r * 19;
        int gy = y0 - 4 + r;
        ldsOff[it] = r * XP + mc * 4;
        rowOff[it] = gy * kNY;
        gxBase[it] = x0 - 8 + mc * 4;
        wr[it]  = vslot;
        okY[it] = vslot && ((unsigned)gy < (unsigned)kNX);
    }

    const float* xb  = x + (size_t)b * kNC * kNX * kNY;
    const int* soaO  = soaTab + o * kNC;
    const float* wO  = w12 + (size_t)(o * kNC) * 9 * W12;

    float acc[4][4];
    #pragma unroll
    for (int jr = 0; jr < 4; ++jr)
        #pragma unroll
        for (int jj = 0; jj < 4; ++jj)
            acc[jr][jj] = 0.0f;

    float4 v[NSTG];                    // prefetch registers (in flight tile)

    // ---- prologue: fetch + publish channel 0 ----
    {
        const int soa = soaO[0];
        #pragma unroll
        for (int it = 0; it < NSTG; ++it) {
            int gx = gxBase[it] + soa;
            float4 t = make_float4(0.f, 0.f, 0.f, 0.f);
            if (okY[it] && (unsigned)gx < (unsigned)kNY)
                t = *(const float4*)(xb + rowOff[it] + gx);
            v[it] = t;
        }
        #pragma unroll
        for (int it = 0; it < NSTG; ++it)
            if (wr[it]) *(float4*)&xtile[0][ldsOff[it]] = v[it];
        __syncthreads();
    }

    for (int c = 0; c < kNC; ++c) {
        const float* xt = &xtile[c & 1][0];

        // --- issue channel c+1 global loads NOW; they complete under the
        //     compute below (T14 async-STAGE split) ---
        if (c + 1 < kNC) {
            const float* xc = xb + (size_t)(c + 1) * kNX * kNY;
            const int soa = soaO[c + 1];
            #pragma unroll
            for (int it = 0; it < NSTG; ++it) {
                int gx = gxBase[it] + soa;
                float4 t = make_float4(0.f, 0.f, 0.f, 0.f);
                if (okY[it] && (unsigned)gx < (unsigned)kNY)
                    t = *(const float4*)(xc + rowOff[it] + gx);
                v[it] = t;
            }
        }
        // pin the prefetch issue above the unrolled compute
        __builtin_amdgcn_sched_barrier(0);

        const float* wch = wO + (size_t)c * 9 * W12;

        // --- compute: input rows m=0..11 feed output rows jr=0..3 (dy=m-jr) ---
        #pragma unroll
        for (int m = 0; m < 12; ++m) {
            const int row = ty * 4 + m;
            const float* p = &xt[row * XP + xo];       // provably 16B aligned
            const float4 q0 = *(const float4*)(p);
            const float4 q1 = *(const float4*)(p + 4);
            const float4 q2 = *(const float4*)(p + 8);
            const float4 q3 = *(const float4*)(p + 12);
            const float xr[16] = { q0.x, q0.y, q0.z, q0.w,
                                   q1.x, q1.y, q1.z, q1.w,
                                   q2.x, q2.y, q2.z, q2.w,
                                   q3.x, q3.y, q3.z, q3.w };

            #pragma unroll
            for (int jr = 0; jr < 4; ++jr) {
                const int dy = m - jr;
                if (dy < 0 || dy >= 9) continue;       // folds at compile time
                // 12 expanded taps, block-uniform -> scalar constant cache
                const float* wrp = wch + dy * W12;
                const float4 wa = *(const float4*)(wrp);
                const float4 wb = *(const float4*)(wrp + 4);
                const float4 wc = *(const float4*)(wrp + 8);

                #pragma unroll
                for (int jj = 0; jj < 4; ++jj) {
                    float a = acc[jr][jj];
                    a = fmaf(wa.x, xr[jj + 0], a);
                    a = fmaf(wa.y, xr[jj + 1], a);
                    a = fmaf(wa.z, xr[jj + 2], a);
                    a = fmaf(wa.w, xr[jj + 3], a);
                    a = fmaf(wb.x, xr[jj + 4], a);
                    a = fmaf(wb.y, xr[jj + 5], a);
                    a = fmaf(wb.z, xr[jj + 6], a);
                    a = fmaf(wb.w, xr[jj + 7], a);
                    a = fmaf(wc.x, xr[jj + 8], a);
                    a = fmaf(wc.y, xr[jj + 9], a);
                    a = fmaf(wc.z, xr[jj + 10], a);
                    a = fmaf(wc.w, xr[jj + 11], a);
                    acc[jr][jj] = a;
                }
            }
        }

        // --- publish channel c+1 into the other buffer; single barrier ---
        if (c + 1 < kNC) {
            float* dst = &xtile[(c + 1) & 1][0];
            #pragma unroll
            for (int it = 0; it < NSTG; ++it)
                if (wr[it]) *(float4*)&dst[ldsOff[it]] = v[it];
            __syncthreads();
        }
    }

    // --- epilogue: 4 rows x 4 cols per thread, aligned float4 stores ---
    #pragma unroll
    for (int jr = 0; jr < 4; ++jr) {
        size_t base = (((size_t)b * kNO + o) * kNX + (size_t)(y0 + ty * 4 + jr)) * kNY
                      + (size_t)(x0 + xo);
        *(float4*)(out + base) = make_float4(acc[jr][0], acc[jr][1],
                                             acc[jr][2], acc[jr][3]);
    }
}

} // namespace

extern "C" void kernel_launch(void* const* d_in, const int* in_sizes, int n_in,
                              void* d_out, int out_size, void* d_ws, size_t ws_size,
                              hipStream_t stream)
{
    const float* x  = (const float*)d_in[0];
    const float* vk = (const float*)d_in[1];
    const int* loc  = (const int*)d_in[2];
    float* outp = (float*)d_out;

    float* w12 = (float*)d_ws;                        // 93*9*12 floats = 40,176 B
    int*   soaTab = (int*)(w12 + NOC * 9 * W12);      // 93 ints

    dim3 pgrid((NOC * 9 * W12 + 255) / 256);
    hipLaunchKernelGGL(prep, pgrid, dim3(256), 0, stream, vk, loc, w12, soaTab);

    dim3 grid(kNY / TX, kNX / TY, kB * kNO);   // (4, 4, 48) = 768 blocks
    hipLaunchKernelGGL(disperse_conv, grid, dim3(256), 0, stream,
                       x, w12, soaTab, outp);
}

// Round 2
// 515.462 us; speedup vs baseline: 3.1694x; 3.1694x over previous
//
#include <hip/hip_runtime.h>

namespace {

constexpr int kB  = 16;
constexpr int kNC = 31;
constexpr int kNX = 256;   // rows (H)
constexpr int kNY = 256;   // cols (W)
constexpr int kNO = 3;
constexpr int kKS = 17;
constexpr int NOC = kNO * kNC;   // 93

constexpr int TX = 64;           // output cols per block
constexpr int TY = 64;           // output rows per block
constexpr int HTY = TY + 8;      // 72 staged rows (halo +-4)
constexpr int XP   = 80;         // pitch (floats). Rows are 20 float4 slots;
                                 // cols 76-79 are pad the compute NEVER reads
                                 // (max read idx = 60+15 = 75), so the tile is
                                 // byte-linear: slot l <-> byte l*16. That is
                                 // exactly what global_load_lds needs
                                 // (wave-uniform base + lane*16).
constexpr int W12  = 12;         // expanded taps (9 + residual shift 0..3)
constexpr int NSLOT = HTY * (XP / 4);        // 1440 16B slots per tile
constexpr int NSTG  = (NSLOT + 255) / 256;   // 6 issues per thread

// ---------------------------------------------------------------------------
// prep: expand each 9-tap weight row to 12 taps with the residual shift rs
// pre-applied (w12[d'] = relu(w[d'-rs]) for d' in [rs,rs+9), else 0), and
// write soaTab[oc] = so & ~3 (the aligned part of the shift, used in staging).
// ---------------------------------------------------------------------------
__global__ void prep(const float* __restrict__ vk, const int* __restrict__ loc,
                     float* __restrict__ w12, int* __restrict__ soaTab)
{
    int i = blockIdx.x * 256 + threadIdx.x;
    if (i < NOC * 9 * W12) {
        int row = i / W12;             // row = oc*9 + dy
        int dp  = i - row * W12;       // d' in [0,12)
        int oc  = row / 9;
        // locations[oc*81] = ((oc*17 + 4)*17) + cx - 4  ->  so = cx - 4
        int so = loc[oc * 81] - (oc * kKS + 4) * kKS;   // in [0,8]
        int rs = so & 3;
        float v = 0.0f;
        if (dp >= rs && dp < rs + 9) {
            float t = vk[row * 9 + (dp - rs)];
            v = t > 0.0f ? t : 0.0f;
        }
        w12[i] = v;
    }
    if (i < NOC) {
        int so = loc[i * 81] - (i * kKS + 4) * kKS;
        soaTab[i] = so & ~3;           // in {0,4,8}
    }
}

// One (batch, order, 64x64 tile) per block. 256 threads as 16x16: each thread
// owns 4 cols x 4 rows. Tile staged pre-shifted by soa -> compute reads are
// STATIC aligned ds_read_b128; residual shift lives in the 12-tap weights.
//
// v3: staging via __builtin_amdgcn_global_load_lds (direct HBM->LDS DMA, no
// VGPR round trip, no spillable register arrays -- v2's 6.4 GB of scratch
// traffic is structurally impossible here). Double-buffered LDS, ONE
// __syncthreads per channel; DMAs for channel c+1 are issued right after the
// barrier and drain at the next barrier, so their latency hides under the
// ~3456-cycle FMA block and never crosses a barrier.
__global__ __launch_bounds__(256, 3)
void disperse_conv(const float* __restrict__ x,
                   const float* __restrict__ w12,
                   const int* __restrict__ soaTab,
                   float* __restrict__ out)
{
    __shared__ __align__(16) float xtile[2][HTY * XP];   // 2 x 23,040 B

    const int tid = threadIdx.x;
    const int x0 = blockIdx.x * TX;
    const int y0 = blockIdx.y * TY;
    const int bz = blockIdx.z;         // 48, order-adjacent: bz = b*3 + o
    const int b  = bz / 3;             // -> 3 orders of same (b,tile) run
    const int o  = bz - 3 * b;         //    together, L2/L3 absorbs x re-read

    const int tx = tid & 15;           // 16 threads across x
    const int ty = tid >> 4;           // 16 threads down y
    const int xo = tx * 4;             // 4 consecutive output cols per thread
    const int wv = tid >> 6;           // wave id 0..3 (for uniform LDS base)

    const float* xb  = x + (size_t)b * kNC * kNX * kNY;
    const int* soaO  = soaTab + o * kNC;
    const float* wO  = w12 + (size_t)(o * kNC) * 9 * W12;

    // ---- stage channel c into buffer nb: 6 DMA issues per thread ----
    // slot l = it*256+tid; r = l/20, mc = l%20; LDS byte = l*16 = r*320+mc*16.
    // OOB halo slots (edge blocks only): skip DMA, ds_write zeros instead
    // (disjoint addresses -> no ordering hazard with the DMA).
    auto stage = [&](int nb, int c) {
        const float* xc  = xb + (size_t)c * (kNX * kNY);
        const int soa    = soaO[c];                    // block-uniform {0,4,8}
        float* dst = &xtile[nb][0];
        #pragma unroll
        for (int it = 0; it < NSTG; ++it) {
            int l  = it * 256 + tid;
            int r  = l / 20;                           // magic-mul, cheap
            int mc = l - r * 20;
            int gy = y0 - 4 + r;
            int gx = x0 + soa - 8 + mc * 4;            // multiple of 4
            bool vslot = (l < NSLOT);
            bool ld = vslot && ((unsigned)gy < (unsigned)kNX)
                            && ((unsigned)gx < (unsigned)kNY);
            if (ld) {
                const float* src = xc + gy * kNY + gx;
                __builtin_amdgcn_global_load_lds(
                    (const __attribute__((address_space(1))) void*)src,
                    (__attribute__((address_space(3))) void*)
                        (dst + it * 1024 + wv * 256),  // wave-uniform base
                    16, 0, 0);                         // + lane*16 by HW
            }
            if (vslot && !ld) {                        // zero the halo slot
                *(float4*)(dst + (size_t)l * 4) = make_float4(0.f, 0.f, 0.f, 0.f);
            }
        }
    };

    float acc[4][4];
    #pragma unroll
    for (int jr = 0; jr < 4; ++jr)
        #pragma unroll
        for (int jj = 0; jj < 4; ++jj)
            acc[jr][jj] = 0.0f;

    // ---- prologue: kick off channel 0 (latency exposed once) ----
    stage(0, 0);

    for (int c = 0; c < kNC; ++c) {
        // Drains this wave's DMAs for channel c (vmcnt(0)) -- nearly free for
        // c>0 since the previous compute covered the latency -- and makes all
        // waves' DMA results visible. Also guarantees buf[(c+1)&1] is no
        // longer being read before we overwrite it below.
        __syncthreads();

        if (c + 1 < kNC)
            stage((c + 1) & 1, c + 1);   // in flight during compute below

        const float* xt  = &xtile[c & 1][0];
        const float* wch = wO + (size_t)c * 9 * W12;

        // --- compute: input rows m=0..11 feed output rows jr=0..3 (dy=m-jr) ---
        #pragma unroll
        for (int m = 0; m < 12; ++m) {
            const int row = ty * 4 + m;
            const float* p = &xt[row * XP + xo];       // 16B aligned
            const float4 q0 = *(const float4*)(p);
            const float4 q1 = *(const float4*)(p + 4);
            const float4 q2 = *(const float4*)(p + 8);
            const float4 q3 = *(const float4*)(p + 12);
            const float xr[16] = { q0.x, q0.y, q0.z, q0.w,
                                   q1.x, q1.y, q1.z, q1.w,
                                   q2.x, q2.y, q2.z, q2.w,
                                   q3.x, q3.y, q3.z, q3.w };

            #pragma unroll
            for (int jr = 0; jr < 4; ++jr) {
                const int dy = m - jr;
                if (dy < 0 || dy >= 9) continue;       // folds at compile time
                // 12 expanded taps, block-uniform -> scalar constant cache
                const float* wrp = wch + dy * W12;
                const float4 wa = *(const float4*)(wrp);
                const float4 wb = *(const float4*)(wrp + 4);
                const float4 wc = *(const float4*)(wrp + 8);

                #pragma unroll
                for (int jj = 0; jj < 4; ++jj) {
                    float a = acc[jr][jj];
                    a = fmaf(wa.x, xr[jj + 0], a);
                    a = fmaf(wa.y, xr[jj + 1], a);
                    a = fmaf(wa.z, xr[jj + 2], a);
                    a = fmaf(wa.w, xr[jj + 3], a);
                    a = fmaf(wb.x, xr[jj + 4], a);
                    a = fmaf(wb.y, xr[jj + 5], a);
                    a = fmaf(wb.z, xr[jj + 6], a);
                    a = fmaf(wb.w, xr[jj + 7], a);
                    a = fmaf(wc.x, xr[jj + 8], a);
                    a = fmaf(wc.y, xr[jj + 9], a);
                    a = fmaf(wc.z, xr[jj + 10], a);
                    a = fmaf(wc.w, xr[jj + 11], a);
                    acc[jr][jj] = a;
                }
            }
        }
    }

    // --- epilogue: 4 rows x 4 cols per thread, aligned float4 stores ---
    #pragma unroll
    for (int jr = 0; jr < 4; ++jr) {
        size_t base = (((size_t)b * kNO + o) * kNX + (size_t)(y0 + ty * 4 + jr)) * kNY
                      + (size_t)(x0 + xo);
        *(float4*)(out + base) = make_float4(acc[jr][0], acc[jr][1],
                                             acc[jr][2], acc[jr][3]);
    }
}

} // namespace

extern "C" void kernel_launch(void* const* d_in, const int* in_sizes, int n_in,
                              void* d_out, int out_size, void* d_ws, size_t ws_size,
                              hipStream_t stream)
{
    const float* x  = (const float*)d_in[0];
    const float* vk = (const float*)d_in[1];
    const int* loc  = (const int*)d_in[2];
    float* outp = (float*)d_out;

    float* w12 = (float*)d_ws;                        // 93*9*12 floats = 40,176 B
    int*   soaTab = (int*)(w12 + NOC * 9 * W12);      // 93 ints

    dim3 pgrid((NOC * 9 * W12 + 255) / 256);
    hipLaunchKernelGGL(prep, pgrid, dim3(256), 0, stream, vk, loc, w12, soaTab);

    dim3 grid(kNY / TX, kNX / TY, kB * kNO);   // (4, 4, 48) = 768 blocks
    hipLaunchKernelGGL(disperse_conv, grid, dim3(256), 0, stream,
                       x, w12, soaTab, outp);
}

// Round 3
// 442.357 us; speedup vs baseline: 3.6931x; 1.1653x over previous
//
#include <hip/hip_runtime.h>

namespace {

constexpr int kB  = 16;
constexpr int kNC = 31;
constexpr int kNX = 256;   // rows (H)
constexpr int kNY = 256;   // cols (W)
constexpr int kNO = 3;
constexpr int kKS = 17;
constexpr int NOC = kNO * kNC;   // 93

constexpr int TX = 64;           // output cols per block
constexpr int TY = 64;           // output rows per block
constexpr int HTY = TY + 8;      // 72 staged rows (halo +-4)
constexpr int XP  = 84;          // pitch (floats) = 21 16B slots. vs 80:
                                 // ty's row stride (4*84=336 dw) is 16 mod 32
                                 // dwords / 5 mod 8 slots -> the four ty
                                 // quarter-waves now SPREAD banks instead of
                                 // aliasing (80: 320 dw = 0 mod 32 -> ty
                                 // invisible, 8-way conflict). 21 slots/row
                                 // keeps the tile byte-linear for the DMA.
constexpr int W12 = 12;          // weight row stride (taps 0..8 used, 9..11 pad)
constexpr int NSLOT = HTY * (XP / 4);        // 1512 16B slots per tile
constexpr int NSTG  = (NSLOT + 255) / 256;   // 6 issues per thread

// ---------------------------------------------------------------------------
// prep: w9[row][t] = relu(vk[row*9+t]) stored at stride 12 (16B-aligned rows,
// taps 9..11 zero). soTab[oc] = full shift so = cx-4 in [0,8]; kernel splits
// it into soa = so & ~3 (staging shift) and rs = so & 3 (compile-time arm).
// ---------------------------------------------------------------------------
__global__ void prep(const float* __restrict__ vk, const int* __restrict__ loc,
                     float* __restrict__ w9, int* __restrict__ soTab)
{
    int i = blockIdx.x * 256 + threadIdx.x;
    if (i < NOC * 9 * W12) {
        int row = i / W12;             // row = oc*9 + dy
        int dp  = i - row * W12;       // tap in [0,12)
        float v = 0.0f;
        if (dp < 9) {
            float t = vk[row * 9 + dp];
            v = t > 0.0f ? t : 0.0f;
        }
        w9[i] = v;
    }
    if (i < NOC) {
        // locations[oc*81] = ((oc*17 + 4)*17) + cx - 4  ->  so = cx - 4
        soTab[i] = loc[i * 81] - (i * kKS + 4) * kKS;   // in [0,8]
    }
}

// Per-channel compute with the residual shift RS as a compile-time constant:
// out[jj] += sum_t w9[t] * xr[jj + RS + t], t = 0..8. Max index 3+3+8 = 14,
// so the same 4x ds_read_b128 window covers every RS. RS==0 needs only 12
// floats -> skips the 4th read.
template<int RS>
__device__ __forceinline__ void compute_channel(const float* __restrict__ xt,
                                                const float* __restrict__ wch,
                                                int ty, int xo, float acc[4][4])
{
    #pragma unroll
    for (int m = 0; m < 12; ++m) {
        const int row = ty * 4 + m;
        const float* p = &xt[row * XP + xo];           // 16B aligned
        const float4 q0 = *(const float4*)(p);
        const float4 q1 = *(const float4*)(p + 4);
        const float4 q2 = *(const float4*)(p + 8);
        float4 q3 = make_float4(0.f, 0.f, 0.f, 0.f);
        if (RS > 0) q3 = *(const float4*)(p + 12);
        const float xr[16] = { q0.x, q0.y, q0.z, q0.w,
                               q1.x, q1.y, q1.z, q1.w,
                               q2.x, q2.y, q2.z, q2.w,
                               q3.x, q3.y, q3.z, q3.w };

        #pragma unroll
        for (int jr = 0; jr < 4; ++jr) {
            const int dy = m - jr;
            if (dy < 0 || dy >= 9) continue;           // folds at compile time
            const float* wrp = wch + dy * W12;         // block-uniform -> SGPR
            const float4 wa = *(const float4*)(wrp);
            const float4 wb = *(const float4*)(wrp + 4);
            const float  w8 = wrp[8];

            #pragma unroll
            for (int jj = 0; jj < 4; ++jj) {
                float a = acc[jr][jj];
                a = fmaf(wa.x, xr[jj + RS + 0], a);
                a = fmaf(wa.y, xr[jj + RS + 1], a);
                a = fmaf(wa.z, xr[jj + RS + 2], a);
                a = fmaf(wa.w, xr[jj + RS + 3], a);
                a = fmaf(wb.x, xr[jj + RS + 4], a);
                a = fmaf(wb.y, xr[jj + RS + 5], a);
                a = fmaf(wb.z, xr[jj + RS + 6], a);
                a = fmaf(wb.w, xr[jj + RS + 7], a);
                a = fmaf(w8,   xr[jj + RS + 8], a);
                acc[jr][jj] = a;
            }
        }
    }
}

// One (batch, order, 64x64 tile) per block. 256 threads as 16x16: each thread
// owns 4 cols x 4 rows. Tile staged pre-shifted by soa via global_load_lds
// (byte-linear dest), double-buffered, one barrier per channel. Residual
// shift rs handled by 4 compile-time arms reading a shifted register window.
__global__ __launch_bounds__(256, 3)
void disperse_conv(const float* __restrict__ x,
                   const float* __restrict__ w9,
                   const int* __restrict__ soTab,
                   float* __restrict__ out)
{
    __shared__ __align__(16) float xtile[2][HTY * XP];   // 2 x 24,192 B

    const int tid = threadIdx.x;
    const int x0 = blockIdx.x * TX;
    const int y0 = blockIdx.y * TY;
    const int bz = blockIdx.z;         // 48, order-adjacent: bz = b*3 + o
    const int b  = bz / 3;             // -> 3 orders of same (b,tile) run
    const int o  = bz - 3 * b;         //    together, L2/L3 absorbs x re-read

    const int tx = tid & 15;           // 16 threads across x
    const int ty = tid >> 4;           // 16 threads down y
    const int xo = tx * 4;             // 4 consecutive output cols per thread
    const int wv = tid >> 6;           // wave id 0..3 (for uniform LDS base)

    const float* xb = x + (size_t)b * kNC * kNX * kNY;
    const int* soO  = soTab + o * kNC;
    const float* wO = w9 + (size_t)(o * kNC) * 9 * W12;

    // ---- stage channel c into buffer nb: 6 DMA issues per thread ----
    // slot l = it*256+tid; r = l/21, mc = l%21; LDS byte = l*16 = r*336+mc*16.
    // OOB halo slots (edge blocks only): skip DMA, ds_write zeros instead
    // (disjoint addresses -> no ordering hazard with the DMA).
    auto stage = [&](int nb, int c) {
        const float* xc = xb + (size_t)c * (kNX * kNY);
        const int soa   = soO[c] & ~3;                 // block-uniform {0,4,8}
        float* dst = &xtile[nb][0];
        #pragma unroll
        for (int it = 0; it < NSTG; ++it) {
            int l  = it * 256 + tid;
            int r  = l / 21;                           // magic-mul, cheap
            int mc = l - r * 21;
            int gy = y0 - 4 + r;
            int gx = x0 + soa - 8 + mc * 4;            // multiple of 4
            bool vslot = (l < NSLOT);
            bool ld = vslot && ((unsigned)gy < (unsigned)kNX)
                            && ((unsigned)gx < (unsigned)kNY);
            if (ld) {
                const float* src = xc + gy * kNY + gx;
                __builtin_amdgcn_global_load_lds(
                    (const __attribute__((address_space(1))) void*)src,
                    (__attribute__((address_space(3))) void*)
                        (dst + it * 1024 + wv * 256),  // wave-uniform base
                    16, 0, 0);                         // + lane*16 by HW
            }
            if (vslot && !ld) {                        // zero the halo slot
                *(float4*)(dst + (size_t)l * 4) = make_float4(0.f, 0.f, 0.f, 0.f);
            }
        }
    };

    float acc[4][4];
    #pragma unroll
    for (int jr = 0; jr < 4; ++jr)
        #pragma unroll
        for (int jj = 0; jj < 4; ++jj)
            acc[jr][jj] = 0.0f;

    // ---- prologue: kick off channel 0 (latency exposed once) ----
    stage(0, 0);

    for (int c = 0; c < kNC; ++c) {
        // Drains this wave's DMAs for channel c (vmcnt(0)) and makes all
        // waves' DMA results visible; also protects buf[(c+1)&1] before the
        // overwrite below. Nearly free for c>0: latency hid under compute.
        __syncthreads();

        if (c + 1 < kNC)
            stage((c + 1) & 1, c + 1);   // in flight during compute below

        const float* xt  = &xtile[c & 1][0];
        const float* wch = wO + (size_t)c * 9 * W12;
        const int rs = soO[c] & 3;                     // block-uniform

        switch (rs) {                                  // scalar branch
            case 0: compute_channel<0>(xt, wch, ty, xo, acc); break;
            case 1: compute_channel<1>(xt, wch, ty, xo, acc); break;
            case 2: compute_channel<2>(xt, wch, ty, xo, acc); break;
            default: compute_channel<3>(xt, wch, ty, xo, acc); break;
        }
    }

    // --- epilogue: 4 rows x 4 cols per thread, aligned float4 stores ---
    #pragma unroll
    for (int jr = 0; jr < 4; ++jr) {
        size_t base = (((size_t)b * kNO + o) * kNX + (size_t)(y0 + ty * 4 + jr)) * kNY
                      + (size_t)(x0 + xo);
        *(float4*)(out + base) = make_float4(acc[jr][0], acc[jr][1],
                                             acc[jr][2], acc[jr][3]);
    }
}

} // namespace

extern "C" void kernel_launch(void* const* d_in, const int* in_sizes, int n_in,
                              void* d_out, int out_size, void* d_ws, size_t ws_size,
                              hipStream_t stream)
{
    const float* x  = (const float*)d_in[0];
    const float* vk = (const float*)d_in[1];
    const int* loc  = (const int*)d_in[2];
    float* outp = (float*)d_out;

    float* w9 = (float*)d_ws;                         // 93*9*12 floats = 40,176 B
    int*   soTab = (int*)(w9 + NOC * 9 * W12);        // 93 ints

    dim3 pgrid((NOC * 9 * W12 + 255) / 256);
    hipLaunchKernelGGL(prep, pgrid, dim3(256), 0, stream, vk, loc, w9, soTab);

    dim3 grid(kNY / TX, kNX / TY, kB * kNO);   // (4, 4, 48) = 768 blocks
    hipLaunchKernelGGL(disperse_conv, grid, dim3(256), 0, stream,
                       x, w9, soTab, outp);
}